// Round 12
// baseline (69.228 us; speedup 1.0000x reference)
//
#include <hip/hip_runtime.h>

#define T_ROWS   16384
#define D_COLS   4096
#define D4       1024          // float4 columns
#define QD_DIM   256
#define H_DIM    128
#define NCHUNK   128
#define ROWS_PER 128           // T_ROWS / NCHUNK
#define NB2      64            // pass-2 blocks (16 col4s each)

typedef float vf4 __attribute__((ext_vector_type(4)));

// ---------------------------------------------------------------------------
// Pass 1: grid (4, NCHUNK+1), 256 thr. y==0 service row: (0,0) -> threshold
// MLP (concurrent, writes out[1]); (1,0) zeroes counter+energies. y>=1
// streams chunk y-1: 256 col4s x 128 rows per block, 8 x 16B loads in
// flight per wave, regular stores. Single-variable change vs R8/R11:
// NCHUNK 512->128 (partial traffic 16.8->4.2 MB each way).
// ---------------------------------------------------------------------------
__global__ void __launch_bounds__(256, 8)
pass1_colsums(const float* __restrict__ E_s, const float* __restrict__ att,
              const float* __restrict__ E_q, const float* __restrict__ W1,
              const float* __restrict__ b1, const float* __restrict__ W2,
              const float* __restrict__ b2,
              float* __restrict__ s_part, float* __restrict__ c_part,
              int* __restrict__ counter, float* __restrict__ energies,
              float* __restrict__ out) {
    const int tid = threadIdx.x;

    if (blockIdx.y == 0) {
        if (blockIdx.x == 1) {
            if (tid == 0) { counter[0] = 0; energies[0] = 0.f; energies[1] = 0.f; }
            return;
        }
        if (blockIdx.x != 0) return;
        // ---- threshold MLP (hidden under the streaming) ----
        __shared__ float eq[QD_DIM];
        eq[tid] = E_q[tid];
        __syncthreads();
        const int row  = tid >> 1;              // 0..127
        const int half = tid & 1;
        const float4* w4 = reinterpret_cast<const float4*>(W1 + (size_t)row * QD_DIM)
                           + half * 32;
        const float4* e4 = reinterpret_cast<const float4*>(eq) + half * 32;
        float acc = 0.f;
        #pragma unroll 8
        for (int k = 0; k < 32; ++k) {
            const float4 w = w4[k];
            const float4 e = e4[k];
            acc = fmaf(w.x, e.x, fmaf(w.y, e.y, fmaf(w.z, e.z, fmaf(w.w, e.w, acc))));
        }
        acc += __shfl_xor(acc, 1);
        const float h = fmaxf(acc + b1[row], 0.f);
        float p = half ? 0.f : W2[row] * h;
        #pragma unroll
        for (int o = 32; o > 0; o >>= 1) p += __shfl_down(p, o);
        __shared__ float red[4];
        if ((tid & 63) == 0) red[tid >> 6] = p;
        __syncthreads();
        if (tid == 0) {
            const float z = red[0] + red[1] + red[2] + red[3] + b2[0];
            out[1] = 1.f / (1.f + expf(-z));
        }
        return;
    }

    // ---- streaming ----
    const int chunk = blockIdx.y - 1;           // 0..NCHUNK-1
    const int c4    = blockIdx.x * 256 + tid;   // float4 column, 0..1023
    const int r0    = chunk * ROWS_PER;

    __shared__ float watt[ROWS_PER];
    if (tid < ROWS_PER) watt[tid] = att[r0 + tid];
    __syncthreads();

    const vf4* p = reinterpret_cast<const vf4*>(E_s) + (size_t)r0 * D4 + c4;
    vf4 s = {0.f, 0.f, 0.f, 0.f};
    vf4 c = {0.f, 0.f, 0.f, 0.f};

    #pragma unroll
    for (int i = 0; i < ROWS_PER / 8; ++i) {
        vf4 v[8];
        #pragma unroll
        for (int j = 0; j < 8; ++j)
            v[j] = p[(size_t)(i * 8 + j) * D4];   // 8 independent 16B loads
        #pragma unroll
        for (int j = 0; j < 8; ++j) {
            const float w = watt[i * 8 + j];
            s += v[j];
            c += v[j] * w;
        }
    }

    const size_t off = (size_t)chunk * D4 + c4;
    reinterpret_cast<vf4*>(s_part)[off] = s;
    reinterpret_cast<vf4*>(c_part)[off] = c;
}

// ---------------------------------------------------------------------------
// Pass 2 + finale. 64 blocks x 512 thr. Thread (w=tid>>6, L=tid&63) owns
// col4 = b*16 + (L&15), chunk-phase (L>>4)+4w (0..31); k = phase+32*i, i<4.
// Wave-loads are 4 x 256B segments. LDS[32][16] combine -> column sums ->
// square -> reduce -> atomicAdd energies; last block writes out[0].
// ---------------------------------------------------------------------------
__global__ void __launch_bounds__(512)
pass2_final(const float* __restrict__ s_part, const float* __restrict__ c_part,
            float* __restrict__ energies, int* __restrict__ counter,
            float* __restrict__ out) {
    const int tid    = threadIdx.x;
    const int L      = tid & 63;
    const int w      = tid >> 6;                // 0..7
    const int c4     = blockIdx.x * 16 + (L & 15);
    const int kphase = (L >> 4) + 4 * w;        // 0..31

    const vf4* s4  = reinterpret_cast<const vf4*>(s_part);
    const vf4* c4p = reinterpret_cast<const vf4*>(c_part);

    vf4 sA = {0.f, 0.f, 0.f, 0.f};
    vf4 cA = {0.f, 0.f, 0.f, 0.f};
    #pragma unroll
    for (int i = 0; i < NCHUNK / 32; ++i) {
        const int k = kphase + 32 * i;
        sA += s4[(size_t)k * D4 + c4];
        cA += c4p[(size_t)k * D4 + c4];
    }

    __shared__ vf4 sh_s[32][16];
    __shared__ vf4 sh_c[32][16];
    sh_s[kphase][L & 15] = sA;
    sh_c[kphase][L & 15] = cA;
    __syncthreads();

    float es = 0.f, ec = 0.f;
    if (tid < 16) {
        vf4 S = {0.f, 0.f, 0.f, 0.f};
        vf4 C = {0.f, 0.f, 0.f, 0.f};
        #pragma unroll
        for (int ph = 0; ph < 32; ++ph) { S += sh_s[ph][tid]; C += sh_c[ph][tid]; }
        es = S.x * S.x + S.y * S.y + S.z * S.z + S.w * S.w;
        ec = C.x * C.x + C.y * C.y + C.z * C.z + C.w * C.w;
    }
    #pragma unroll
    for (int o = 8; o > 0; o >>= 1) {
        es += __shfl_down(es, o);
        ec += __shfl_down(ec, o);
    }

    if (tid == 0) {
        atomicAdd(&energies[0], es);
        atomicAdd(&energies[1], ec);
        __threadfence();
        const int old = atomicAdd(counter, 1);
        if (old == NB2 - 1) {
            const float tes = atomicAdd(&energies[0], 0.f);  // coherent read-back
            const float tec = atomicAdd(&energies[1], 0.f);
            out[0] = tec / tes;
        }
    }
}

// ---------------------------------------------------------------------------
extern "C" void kernel_launch(void* const* d_in, const int* in_sizes, int n_in,
                              void* d_out, int out_size, void* d_ws, size_t ws_size,
                              hipStream_t stream) {
    const float* E_s = (const float*)d_in[0];
    const float* E_q = (const float*)d_in[1];
    const float* att = (const float*)d_in[2];
    const float* W1  = (const float*)d_in[3];
    const float* b1  = (const float*)d_in[4];
    const float* W2  = (const float*)d_in[5];
    const float* b2  = (const float*)d_in[6];
    float* out = (float*)d_out;
    float* ws  = (float*)d_ws;

    // ws layout: s_part | c_part | energies[2] | counter  (~4.2 MB)
    float* s_part   = ws;
    float* c_part   = s_part + (size_t)NCHUNK * D_COLS;
    float* energies = c_part + (size_t)NCHUNK * D_COLS;
    int*   counter  = (int*)(energies + 2);

    pass1_colsums<<<dim3(4, NCHUNK + 1), 256, 0, stream>>>(
        E_s, att, E_q, W1, b1, W2, b2, s_part, c_part, counter, energies, out);
    pass2_final<<<NB2, 512, 0, stream>>>(s_part, c_part, energies, counter, out);
}

// Round 13
// 53.898 us; speedup vs baseline: 1.2844x; 1.2844x over previous
//
#include <hip/hip_runtime.h>

#define T_ROWS   16384
#define D_COLS   4096
#define D4       1024          // float4 columns
#define QD_DIM   256
#define H_DIM    128
#define NCHUNK   512
#define ROWS_PER 32            // T_ROWS / NCHUNK
#define NB2      64            // pass-2 blocks (16 col4s each)

typedef float vf4 __attribute__((ext_vector_type(4)));

// ---------------------------------------------------------------------------
// Best measured structure (R8/R11: 53.8/53.9 us).
// Pass 1: grid (4, NCHUNK+1), 256 thr. y==0 service row: (0,0) -> threshold
// MLP (concurrent with the stream, writes out[1]); (1,0) zeroes
// counter+energies. y>=1 streams chunk y-1: 256 col4s x 32 rows per block,
// 8 x 16B loads in flight per wave, regular stores (partials stay
// cache-resident for pass 2 — NT stores and traffic-halving both measured
// slower: R9/R10/R12).
// ---------------------------------------------------------------------------
__global__ void __launch_bounds__(256, 8)
pass1_colsums(const float* __restrict__ E_s, const float* __restrict__ att,
              const float* __restrict__ E_q, const float* __restrict__ W1,
              const float* __restrict__ b1, const float* __restrict__ W2,
              const float* __restrict__ b2,
              float* __restrict__ s_part, float* __restrict__ c_part,
              int* __restrict__ counter, float* __restrict__ energies,
              float* __restrict__ out) {
    const int tid = threadIdx.x;

    if (blockIdx.y == 0) {
        if (blockIdx.x == 1) {
            if (tid == 0) { counter[0] = 0; energies[0] = 0.f; energies[1] = 0.f; }
            return;
        }
        if (blockIdx.x != 0) return;
        // ---- threshold MLP (hidden under the streaming) ----
        __shared__ float eq[QD_DIM];
        eq[tid] = E_q[tid];
        __syncthreads();
        const int row  = tid >> 1;              // 0..127
        const int half = tid & 1;
        const float4* w4 = reinterpret_cast<const float4*>(W1 + (size_t)row * QD_DIM)
                           + half * 32;
        const float4* e4 = reinterpret_cast<const float4*>(eq) + half * 32;
        float acc = 0.f;
        #pragma unroll 8
        for (int k = 0; k < 32; ++k) {
            const float4 w = w4[k];
            const float4 e = e4[k];
            acc = fmaf(w.x, e.x, fmaf(w.y, e.y, fmaf(w.z, e.z, fmaf(w.w, e.w, acc))));
        }
        acc += __shfl_xor(acc, 1);
        const float h = fmaxf(acc + b1[row], 0.f);
        float p = half ? 0.f : W2[row] * h;
        #pragma unroll
        for (int o = 32; o > 0; o >>= 1) p += __shfl_down(p, o);
        __shared__ float red[4];
        if ((tid & 63) == 0) red[tid >> 6] = p;
        __syncthreads();
        if (tid == 0) {
            const float z = red[0] + red[1] + red[2] + red[3] + b2[0];
            out[1] = 1.f / (1.f + expf(-z));
        }
        return;
    }

    // ---- streaming ----
    const int chunk = blockIdx.y - 1;           // 0..NCHUNK-1
    const int c4    = blockIdx.x * 256 + tid;   // float4 column, 0..1023
    const int r0    = chunk * ROWS_PER;

    __shared__ float watt[ROWS_PER];
    if (tid < ROWS_PER) watt[tid] = att[r0 + tid];
    __syncthreads();

    const vf4* p = reinterpret_cast<const vf4*>(E_s) + (size_t)r0 * D4 + c4;
    vf4 s = {0.f, 0.f, 0.f, 0.f};
    vf4 c = {0.f, 0.f, 0.f, 0.f};

    #pragma unroll
    for (int i = 0; i < ROWS_PER / 8; ++i) {
        vf4 v[8];
        #pragma unroll
        for (int j = 0; j < 8; ++j)
            v[j] = p[(size_t)(i * 8 + j) * D4];   // 8 independent 16B loads
        #pragma unroll
        for (int j = 0; j < 8; ++j) {
            const float w = watt[i * 8 + j];
            s += v[j];
            c += v[j] * w;
        }
    }

    const size_t off = (size_t)chunk * D4 + c4;
    reinterpret_cast<vf4*>(s_part)[off] = s;
    reinterpret_cast<vf4*>(c_part)[off] = c;
}

// ---------------------------------------------------------------------------
// Pass 2 + finale. 64 blocks x 512 thr (8 waves). Thread (w=tid>>6, L=tid&63)
// owns col4 = b*16 + (L&15), chunk-phase (L>>4)+4w (0..31); k = phase+32*i,
// i<16. Wave-loads are 4 x 256B segments. LDS[32][16] combine -> column sums
// -> square -> reduce -> atomicAdd energies; last block writes out[0].
// ---------------------------------------------------------------------------
__global__ void __launch_bounds__(512)
pass2_final(const float* __restrict__ s_part, const float* __restrict__ c_part,
            float* __restrict__ energies, int* __restrict__ counter,
            float* __restrict__ out) {
    const int tid    = threadIdx.x;
    const int L      = tid & 63;
    const int w      = tid >> 6;                // 0..7
    const int c4     = blockIdx.x * 16 + (L & 15);
    const int kphase = (L >> 4) + 4 * w;        // 0..31

    const vf4* s4  = reinterpret_cast<const vf4*>(s_part);
    const vf4* c4p = reinterpret_cast<const vf4*>(c_part);

    vf4 sA = {0.f, 0.f, 0.f, 0.f};
    vf4 cA = {0.f, 0.f, 0.f, 0.f};
    #pragma unroll 8
    for (int i = 0; i < NCHUNK / 32; ++i) {
        const int k = kphase + 32 * i;
        sA += s4[(size_t)k * D4 + c4];
        cA += c4p[(size_t)k * D4 + c4];
    }

    __shared__ vf4 sh_s[32][16];
    __shared__ vf4 sh_c[32][16];
    sh_s[kphase][L & 15] = sA;
    sh_c[kphase][L & 15] = cA;
    __syncthreads();

    float es = 0.f, ec = 0.f;
    if (tid < 16) {
        vf4 S = {0.f, 0.f, 0.f, 0.f};
        vf4 C = {0.f, 0.f, 0.f, 0.f};
        #pragma unroll
        for (int ph = 0; ph < 32; ++ph) { S += sh_s[ph][tid]; C += sh_c[ph][tid]; }
        es = S.x * S.x + S.y * S.y + S.z * S.z + S.w * S.w;
        ec = C.x * C.x + C.y * C.y + C.z * C.z + C.w * C.w;
    }
    #pragma unroll
    for (int o = 8; o > 0; o >>= 1) {
        es += __shfl_down(es, o);
        ec += __shfl_down(ec, o);
    }

    if (tid == 0) {
        atomicAdd(&energies[0], es);
        atomicAdd(&energies[1], ec);
        __threadfence();
        const int old = atomicAdd(counter, 1);
        if (old == NB2 - 1) {
            const float tes = atomicAdd(&energies[0], 0.f);  // coherent read-back
            const float tec = atomicAdd(&energies[1], 0.f);
            out[0] = tec / tes;
        }
    }
}

// ---------------------------------------------------------------------------
extern "C" void kernel_launch(void* const* d_in, const int* in_sizes, int n_in,
                              void* d_out, int out_size, void* d_ws, size_t ws_size,
                              hipStream_t stream) {
    const float* E_s = (const float*)d_in[0];
    const float* E_q = (const float*)d_in[1];
    const float* att = (const float*)d_in[2];
    const float* W1  = (const float*)d_in[3];
    const float* b1  = (const float*)d_in[4];
    const float* W2  = (const float*)d_in[5];
    const float* b2  = (const float*)d_in[6];
    float* out = (float*)d_out;
    float* ws  = (float*)d_ws;

    // ws layout: s_part | c_part | energies[2] | counter  (~16.8 MB)
    float* s_part   = ws;
    float* c_part   = s_part + (size_t)NCHUNK * D_COLS;
    float* energies = c_part + (size_t)NCHUNK * D_COLS;
    int*   counter  = (int*)(energies + 2);

    pass1_colsums<<<dim3(4, NCHUNK + 1), 256, 0, stream>>>(
        E_s, att, E_q, W1, b1, W2, b2, s_part, c_part, counter, energies, out);
    pass2_final<<<NB2, 512, 0, stream>>>(s_part, c_part, energies, counter, out);
}